// Round 4
// baseline (427.625 us; speedup 1.0000x reference)
//
#include <hip/hip_runtime.h>
#include <math.h>

#define NB   4
#define NN   4096
#define FIN  128
#define FOUT 128   // H*U
#define NH   4
#define UU   32

__device__ __forceinline__ unsigned short f2bf(float f) {
    unsigned u = __float_as_uint(f);
    u += 0x7fff + ((u >> 16) & 1);          // round-to-nearest-even
    return (unsigned short)(u >> 16);
}

// ---------------- Kernel 1: hfeat(bf16) = x@W ; f1 = h·a_src ; f2 = h·a_dst ----------------
#define K1_ROWS 64
#define K1_RT   8
#define K1_CT   4
#define XPAD    132

__global__ __launch_bounds__(256) void k1_feat(
    const float* __restrict__ x, const float* __restrict__ W,
    const float* __restrict__ a_src, const float* __restrict__ a_dst,
    unsigned short* __restrict__ hbf, float* __restrict__ f1g, float* __restrict__ f2g)
{
    __shared__ __align__(16) float Wq[32 * FOUT];
    __shared__ __align__(16) float xs[K1_ROWS * XPAD];

    const int tid  = threadIdx.x;
    const int row0 = blockIdx.x * K1_ROWS;

    const float4* x4 = (const float4*)(x + (size_t)row0 * FIN);
    for (int idx = tid; idx < K1_ROWS * FIN / 4; idx += 256) {
        int r = idx >> 5, q = idx & 31;
        *(float4*)(xs + r * XPAD + q * 4) = x4[idx];
    }

    const int cg = tid & 31;
    const int rg = tid >> 5;
    float acc[K1_RT][K1_CT];
    #pragma unroll
    for (int rr = 0; rr < K1_RT; rr++)
        #pragma unroll
        for (int cc = 0; cc < K1_CT; cc++) acc[rr][cc] = 0.f;

    for (int kt = 0; kt < 4; kt++) {
        __syncthreads();
        for (int idx = tid; idx < 32 * FOUT / 4; idx += 256)
            ((float4*)Wq)[idx] = ((const float4*)W)[kt * 1024 + idx];
        __syncthreads();
        #pragma unroll
        for (int k4 = 0; k4 < 8; k4++) {
            const int kb = kt * 32 + k4 * 4;
            float4 xv[K1_RT];
            #pragma unroll
            for (int rr = 0; rr < K1_RT; rr++)
                xv[rr] = *(const float4*)(xs + (rg * K1_RT + rr) * XPAD + kb);
            #pragma unroll
            for (int kk = 0; kk < 4; kk++) {
                float wv[K1_CT];
                #pragma unroll
                for (int cc = 0; cc < K1_CT; cc++)
                    wv[cc] = Wq[(k4 * 4 + kk) * FOUT + cg + 32 * cc];
                #pragma unroll
                for (int rr = 0; rr < K1_RT; rr++) {
                    float xk = ((const float*)&xv[rr])[kk];
                    #pragma unroll
                    for (int cc = 0; cc < K1_CT; cc++)
                        acc[rr][cc] = fmaf(xk, wv[cc], acc[rr][cc]);
                }
            }
        }
    }
    __syncthreads();
    #pragma unroll
    for (int rr = 0; rr < K1_RT; rr++)
        #pragma unroll
        for (int cc = 0; cc < K1_CT; cc++)
            xs[(rg * K1_RT + rr) * XPAD + cg + 32 * cc] = acc[rr][cc];
    __syncthreads();

    // bf16 store of h (gather table), 8 channels / thread / iter
    unsigned short* hrow = hbf + (size_t)row0 * FOUT;
    for (int idx = tid; idx < K1_ROWS * FOUT / 8; idx += 256) {
        int r = idx >> 4, q = idx & 15;
        const float* src = xs + r * XPAD + q * 8;
        uint4 o;
        o.x = (unsigned)f2bf(src[0]) | ((unsigned)f2bf(src[1]) << 16);
        o.y = (unsigned)f2bf(src[2]) | ((unsigned)f2bf(src[3]) << 16);
        o.z = (unsigned)f2bf(src[4]) | ((unsigned)f2bf(src[5]) << 16);
        o.w = (unsigned)f2bf(src[6]) | ((unsigned)f2bf(src[7]) << 16);
        *(uint4*)(hrow + (size_t)r * FOUT + q * 8) = o;
    }

    for (int task = tid; task < K1_ROWS * NH * 2; task += 256) {
        int row = task >> 3;
        int head = (task >> 1) & 3;
        int which = task & 1;
        const float* av = which ? a_dst : a_src;
        float s = 0.f;
        #pragma unroll
        for (int u = 0; u < UU; u++)
            s += xs[row * XPAD + head * UU + u] * av[head * UU + u];
        float* dst = which ? f2g : f1g;
        dst[(size_t)(row0 + row) * NH + head] = s;
    }
}

// ---------------- Kernel 2: per-row sparse GAT (fully deterministic: no atomics) ----------------
#define CAP   512
#define APAD  516
#define PPART 132

__device__ __forceinline__ float lrelu(float e) { return e > 0.f ? e : 0.2f * e; }

__global__ __launch_bounds__(256) void k2_gat(
    const float* __restrict__ adj, const unsigned short* __restrict__ hbf,
    const float* __restrict__ f1g, const float* __restrict__ f2g,
    const float* __restrict__ bias, float* __restrict__ out)
{
    // XCD-aware swizzle: XCDs {2b,2b+1} serve batch b -> per-XCD gather set = 1 MB (L2-resident)
    const int q    = blockIdx.x;
    const int xcd  = q & 7;
    const int b    = xcd >> 1;
    const int i    = ((q >> 3) << 1) | (xcd & 1);
    const int row  = b * NN + i;
    const int tid  = threadIdx.x;
    const int lane = tid & 63;
    const int wv   = tid >> 6;

    __shared__ int   nbr[CAP];
    __shared__ float alpha[NH][APAD];
    __shared__ float part[16][PPART];
    __shared__ float inv_s[NH];
    __shared__ int   wcnt[4];

    // ---- Phase A pass 1: load adj chunk, count matches per wave (registers + ballots only)
    const float4* arow = (const float4*)(adj + (size_t)row * NN);
    float4 v[4];
    #pragma unroll
    for (int it = 0; it < 4; it++)
        v[it] = arow[wv * 256 + it * 64 + lane];   // all 4 loads in flight first

    const unsigned long long below = (1ull << lane) - 1ull;
    int my_cnt = 0;
    #pragma unroll
    for (int it = 0; it < 4; it++) {
        const int jb = (wv * 256 + it * 64 + lane) << 2;
        my_cnt += __popcll(__ballot((v[it].x > 0.f) | (jb + 0 == i)));
        my_cnt += __popcll(__ballot((v[it].y > 0.f) | (jb + 1 == i)));
        my_cnt += __popcll(__ballot((v[it].z > 0.f) | (jb + 2 == i)));
        my_cnt += __popcll(__ballot((v[it].w > 0.f) | (jb + 3 == i)));
    }
    if (lane == 0) wcnt[wv] = my_cnt;
    __syncthreads();

    // deterministic exclusive prefix over the 4 wave counts (every lane computes it)
    const int w0 = wcnt[0], w1 = wcnt[1], w2 = wcnt[2], w3 = wcnt[3];
    int run = (wv > 0 ? w0 : 0) + (wv > 1 ? w1 : 0) + (wv > 2 ? w2 : 0);
    const int total = w0 + w1 + w2 + w3;
    const int K = (total < CAP) ? total : CAP;

    // ---- Phase A pass 2: recompute ballots, write nbr + fused scores at fixed slots
    const float4* f2b = (const float4*)(f2g + (size_t)b * NN * NH);
    const float4  f1v = ((const float4*)f1g)[row];
    #pragma unroll
    for (int it = 0; it < 4; it++) {
        const int jb = (wv * 256 + it * 64 + lane) << 2;
        const bool p0 = (v[it].x > 0.f) | (jb + 0 == i);
        const bool p1 = (v[it].y > 0.f) | (jb + 1 == i);
        const bool p2 = (v[it].z > 0.f) | (jb + 2 == i);
        const bool p3 = (v[it].w > 0.f) | (jb + 3 == i);
        unsigned long long m0 = __ballot(p0), m1 = __ballot(p1);
        unsigned long long m2 = __ballot(p2), m3 = __ballot(p3);
        int c0 = __popcll(m0), c1 = __popcll(m1), c2 = __popcll(m2), c3 = __popcll(m3);
        #pragma unroll
        for (int e = 0; e < 4; e++) {
            bool pe = e == 0 ? p0 : e == 1 ? p1 : e == 2 ? p2 : p3;
            unsigned long long me = e == 0 ? m0 : e == 1 ? m1 : e == 2 ? m2 : m3;
            int pre = e == 0 ? 0 : e == 1 ? c0 : e == 2 ? c0 + c1 : c0 + c1 + c2;
            if (pe) {
                int p = run + pre + __popcll(me & below);
                if (p < CAP) {
                    int j = jb + e;
                    nbr[p] = j;
                    float4 f2v = f2b[j];
                    alpha[0][p] = lrelu(f1v.x + f2v.x);
                    alpha[1][p] = lrelu(f1v.y + f2v.y);
                    alpha[2][p] = lrelu(f1v.z + f2v.z);
                    alpha[3][p] = lrelu(f1v.w + f2v.w);
                }
            }
        }
        run += c0 + c1 + c2 + c3;
    }
    __syncthreads();

    // ---- Softmax stats: wave wv owns head wv (store unnormalized exp)
    {
        float m = -1e30f;
        for (int k = lane; k < K; k += 64) m = fmaxf(m, alpha[wv][k]);
        #pragma unroll
        for (int off = 32; off > 0; off >>= 1) m = fmaxf(m, __shfl_xor(m, off, 64));
        float s = 0.f;
        for (int k = lane; k < K; k += 64) {
            float a = __expf(alpha[wv][k] - m);
            alpha[wv][k] = a;
            s += a;
        }
        #pragma unroll
        for (int off = 32; off > 0; off >>= 1) s += __shfl_xor(s, off, 64);
        if (lane == 0) inv_s[wv] = 1.f / s;
    }
    __syncthreads();

    // ---- Phase C: bf16x8 gather per lane, 16-way k split, 2x unroll
    const int cq = tid & 15;       // 8 channels: c = cq*8
    const int kg = tid >> 4;       // 0..15
    const int hh = cq >> 2;        // head
    const unsigned short* hb = hbf + (size_t)b * NN * FOUT + cq * 8;
    float acc[8];
    #pragma unroll
    for (int t = 0; t < 8; t++) acc[t] = 0.f;

    int k = kg;
    for (; k + 16 < K; k += 32) {
        int j0 = nbr[k], j1 = nbr[k + 16];
        float a0 = alpha[hh][k], a1 = alpha[hh][k + 16];
        uint4 u4a = *(const uint4*)(hb + (size_t)j0 * FOUT);
        uint4 u4b = *(const uint4*)(hb + (size_t)j1 * FOUT);
        const unsigned* u0 = (const unsigned*)&u4a;
        const unsigned* u1 = (const unsigned*)&u4b;
        #pragma unroll
        for (int t = 0; t < 4; t++) {
            acc[2*t]   = fmaf(a0, __uint_as_float(u0[t] << 16),          acc[2*t]);
            acc[2*t+1] = fmaf(a0, __uint_as_float(u0[t] & 0xffff0000u),  acc[2*t+1]);
        }
        #pragma unroll
        for (int t = 0; t < 4; t++) {
            acc[2*t]   = fmaf(a1, __uint_as_float(u1[t] << 16),          acc[2*t]);
            acc[2*t+1] = fmaf(a1, __uint_as_float(u1[t] & 0xffff0000u),  acc[2*t+1]);
        }
    }
    if (k < K) {
        int j0 = nbr[k];
        float a0 = alpha[hh][k];
        uint4 u4a = *(const uint4*)(hb + (size_t)j0 * FOUT);
        const unsigned* u0 = (const unsigned*)&u4a;
        #pragma unroll
        for (int t = 0; t < 4; t++) {
            acc[2*t]   = fmaf(a0, __uint_as_float(u0[t] << 16),          acc[2*t]);
            acc[2*t+1] = fmaf(a0, __uint_as_float(u0[t] & 0xffff0000u),  acc[2*t+1]);
        }
    }
    *(float4*)&part[kg][cq * 8]     = *(float4*)&acc[0];
    *(float4*)&part[kg][cq * 8 + 4] = *(float4*)&acc[4];
    __syncthreads();

    // ---- Epilogue
    if (tid < FOUT) {
        float o = 0.f;
        #pragma unroll
        for (int g = 0; g < 16; g++) o += part[g][tid];
        o = o * inv_s[tid >> 5] + bias[tid];
        o = o > 0.f ? o : expm1f(o);
        out[(size_t)row * FOUT + tid] = o;
    }
}

extern "C" void kernel_launch(void* const* d_in, const int* in_sizes, int n_in,
                              void* d_out, int out_size, void* d_ws, size_t ws_size,
                              hipStream_t stream) {
    const float* x     = (const float*)d_in[0];
    const float* adj   = (const float*)d_in[1];
    const float* W     = (const float*)d_in[2];
    const float* a_src = (const float*)d_in[3];
    const float* a_dst = (const float*)d_in[4];
    const float* bias  = (const float*)d_in[5];
    float* out = (float*)d_out;

    char* ws = (char*)d_ws;
    unsigned short* hbf = (unsigned short*)ws;                        // 4 MB bf16
    float* f1g = (float*)(ws + (size_t)NB * NN * FOUT * 2);           // 256 KB
    float* f2g = f1g + (size_t)NB * NN * NH;                          // 256 KB

    k1_feat<<<NB * NN / K1_ROWS, 256, 0, stream>>>(x, W, a_src, a_dst, hbf, f1g, f2g);
    k2_gat<<<NB * NN, 256, 0, stream>>>(adj, hbf, f1g, f2g, bias, out);
}